// Round 6
// baseline (1044.346 us; speedup 1.0000x reference)
//
#include <hip/hip_runtime.h>

#define NN 100000
#define EE 400000
#define HH 512
#define NB_SCAN 98   // ceil(NN/1024)

typedef __attribute__((ext_vector_type(8))) short short8;
typedef __attribute__((ext_vector_type(8))) unsigned short ushort8;
typedef __attribute__((ext_vector_type(4))) float f32x4;

__device__ inline unsigned short f2b(float f) {   // f32 -> bf16 RNE
    unsigned int u = __float_as_uint(f);
    return (unsigned short)((u + 0x7fffu + ((u >> 16) & 1u)) >> 16);
}
__device__ inline float b2f(unsigned short b) {
    return __uint_as_float(((unsigned int)b) << 16);
}

// ================= CSR build =================
__global__ void histo_deg(const int* __restrict__ dst, int* __restrict__ deg) {
    int e = blockIdx.x * blockDim.x + threadIdx.x;
    if (e < EE) atomicAdd(&deg[dst[e]], 1);
}

__global__ void scan_reduce(const int* __restrict__ deg, int* __restrict__ blockSums) {
    __shared__ int s[256];
    int b = blockIdx.x, t = threadIdx.x;
    int base = b * 1024 + t * 4;
    int v = 0;
    #pragma unroll
    for (int j = 0; j < 4; ++j) { int i = base + j; if (i < NN) v += deg[i]; }
    s[t] = v; __syncthreads();
    for (int off = 128; off > 0; off >>= 1) {
        if (t < off) s[t] += s[t + off];
        __syncthreads();
    }
    if (t == 0) blockSums[b] = s[0];
}

__global__ void scan_top(int* __restrict__ blockSums, int* __restrict__ start) {
    __shared__ int s[128];
    int t = threadIdx.x;
    s[t] = (t < NB_SCAN) ? blockSums[t] : 0;
    __syncthreads();
    for (int off = 1; off < 128; off <<= 1) {
        int u = (t >= off) ? s[t - off] : 0;
        __syncthreads();
        s[t] += u;
        __syncthreads();
    }
    if (t < NB_SCAN) blockSums[t] = (t == 0) ? 0 : s[t - 1];  // exclusive
    if (t == 0) start[NN] = EE;
}

__global__ void scan_down(const int* __restrict__ deg, const int* __restrict__ blockSums,
                          int* __restrict__ start, int* __restrict__ cursor) {
    __shared__ int s[256];
    int b = blockIdx.x, t = threadIdx.x;
    int base = b * 1024 + t * 4;
    int v[4]; int sum = 0;
    #pragma unroll
    for (int j = 0; j < 4; ++j) {
        int i = base + j;
        v[j] = (i < NN) ? deg[i] : 0;
        sum += v[j];
    }
    s[t] = sum; __syncthreads();
    for (int off = 1; off < 256; off <<= 1) {
        int u = (t >= off) ? s[t - off] : 0;
        __syncthreads();
        s[t] += u;
        __syncthreads();
    }
    int excl = blockSums[b] + ((t == 0) ? 0 : s[t - 1]);
    #pragma unroll
    for (int j = 0; j < 4; ++j) {
        int i = base + j;
        if (i < NN) { start[i] = excl; cursor[i] = excl; excl += v[j]; }
    }
}

__global__ void csr_fill(const int* __restrict__ src, const int* __restrict__ dst,
                         int* __restrict__ cursor, int* __restrict__ eidx) {
    int e = blockIdx.x * blockDim.x + threadIdx.x;
    if (e < EE) {
        int p = atomicAdd(&cursor[dst[e]], 1);
        eidx[p] = src[e];
    }
}

// ================= Weight transpose + bf16 convert =================
__global__ void w_transpose(const float* __restrict__ w, unsigned short* __restrict__ wt) {
    int idx = blockIdx.x * 256 + threadIdx.x;  // n*512 + k, k fastest
    int n = idx >> 9, k = idx & 511;
    wt[idx] = f2b(w[(size_t)k * HH + n]);
}

// ================= Aggregation: bf16 gather, one wave per node =================
__global__ __launch_bounds__(256) void gather_rows_b(
    const unsigned short* __restrict__ xb, const int* __restrict__ start,
    const int* __restrict__ eidx, unsigned short* __restrict__ agg)
{
    int node = blockIdx.x * 4 + (threadIdx.x >> 6);
    if (node >= NN) return;
    int c0 = (threadIdx.x & 63) << 3;   // 8 bf16 per lane
    float a[8] = {0.f,0.f,0.f,0.f,0.f,0.f,0.f,0.f};
    int e1 = start[node + 1];
    for (int e = start[node]; e < e1; ++e) {
        ushort8 v = *(const ushort8*)(xb + (size_t)eidx[e] * HH + c0);
        #pragma unroll
        for (int j = 0; j < 8; ++j) a[j] += b2f(v[j]);
    }
    ushort8 o;
    #pragma unroll
    for (int j = 0; j < 8; ++j) o[j] = f2b(a[j]);
    *(ushort8*)(agg + (size_t)node * HH + c0) = o;
}

// Layer-1 scalar aggregate via CSR
__global__ void gather_scalar(const float* __restrict__ x, const int* __restrict__ start,
                              const int* __restrict__ eidx, float* __restrict__ agg0) {
    int i = blockIdx.x * blockDim.x + threadIdx.x;
    if (i >= NN) return;
    float s = 0.f;
    int e1 = start[i + 1];
    for (int e = start[i]; e < e1; ++e) s += x[eidx[e]];
    agg0[i] = s;
}

// x1[i][h] = relu(agg0[i]*w_rel[h] + b[h] + x[i]*w_root[h]); writes f32 + bf16
__global__ void layer1_expand(const float* __restrict__ x,
                              const float* __restrict__ agg0,
                              const float* __restrict__ w_rel,
                              const float* __restrict__ b,
                              const float* __restrict__ w_root,
                              float* __restrict__ x1,
                              unsigned short* __restrict__ x1b) {
    int idx = blockIdx.x * blockDim.x + threadIdx.x;
    int i = idx >> 7;
    if (i >= NN) return;
    int q = (idx & 127) << 2;
    float a = agg0[i], xv = x[i];
    float4 wr = *(const float4*)&w_rel[q];
    float4 bb = *(const float4*)&b[q];
    float4 wt = *(const float4*)&w_root[q];
    float4 o;
    o.x = fmaxf(fmaf(a, wr.x, fmaf(xv, wt.x, bb.x)), 0.f);
    o.y = fmaxf(fmaf(a, wr.y, fmaf(xv, wt.y, bb.y)), 0.f);
    o.z = fmaxf(fmaf(a, wr.z, fmaf(xv, wt.z, bb.z)), 0.f);
    o.w = fmaxf(fmaf(a, wr.w, fmaf(xv, wt.w, bb.w)), 0.f);
    *(float4*)&x1[(size_t)i * HH + q] = o;
    ushort4 ob = { f2b(o.x), f2b(o.y), f2b(o.z), f2b(o.w) };
    *(ushort4*)&x1b[(size_t)i * HH + q] = ob;
}

// ================= MFMA GEMM =================
// out = (relu?)(AB@WrT^T + XBp@WoT^T + bias) + resid
// 128x128 tile, BK=32, 4 waves. 3-buffer LDS pipeline, prefetch depth 2,
// counted s_waitcnt vmcnt(4) (never 0 in main loop) + raw s_barrier.
// LDS k-slots XOR-swizzled both sides (conflict-free, verified R4).
__device__ inline void gload16(const void* g, void* l) {
    __builtin_amdgcn_global_load_lds(
        (const __attribute__((address_space(1))) unsigned int*)g,
        (__attribute__((address_space(3))) unsigned int*)l,
        16, 0, 0);
}

template<bool RELU, bool RB16, bool WF32, bool WB16>
__global__ __launch_bounds__(256, 2) void gemm_mfma(
    const unsigned short* __restrict__ AB, const unsigned short* __restrict__ XBp,
    const unsigned short* __restrict__ WrT, const unsigned short* __restrict__ WoT,
    const float* __restrict__ bias, const void* __restrict__ residv,
    float* __restrict__ out, unsigned short* __restrict__ outb)
{
    __shared__ unsigned short As[3 * 128 * 32];  // [buf][row][k], k-slots swizzled
    __shared__ unsigned short Bs[3 * 128 * 32];  // [buf][col][k]
    const int tid  = threadIdx.x;
    const int wave = tid >> 6, lane = tid & 63;

    // Bijective XCD-chunked mapping: 3128 blocks = 8 XCDs x 391.
    const int bid = blockIdx.x;
    const int nid = (bid & 7) * 391 + (bid >> 3);
    const int col0 = (nid & 3) << 7;   // n-tile fastest within chunk -> A-panel L2 reuse
    const int row0 = (nid >> 2) << 7;

    const int wr = wave >> 1, wc = wave & 1; // wave's 64x64 quadrant
    const int l16 = lane & 15, lq = lane >> 4;
    const int sRow = lane >> 2;                                  // staging row in chunk
    const int sColSwz = (((lane & 3) ^ ((lane >> 3) & 3)) << 3); // swizzled k-slot (shorts)
    const int xorslot = ((lq ^ ((lane >> 1) & 3)) << 3);         // read-side slot (shorts)

    // Precompute staged global rows/cols (clamped; stores guarded)
    int rowA[2], colB[2];
    #pragma unroll
    for (int i = 0; i < 2; ++i) {
        int chunk = (wave << 1) + i;
        int gr = row0 + chunk * 16 + sRow;
        rowA[i] = (gr >= NN) ? (NN - 1) : gr;
        colB[i] = col0 + chunk * 16 + sRow;
    }

    f32x4 acc[4][4];
    #pragma unroll
    for (int m = 0; m < 4; ++m)
        #pragma unroll
        for (int n = 0; n < 4; ++n)
            acc[m][n] = (f32x4){0.f, 0.f, 0.f, 0.f};

    auto STAGE = [&](unsigned short* Asb, unsigned short* Bsb, int t) {
        const int k0 = t << 5;
        const unsigned short* Ap = (k0 < 512) ? AB  : XBp;
        const unsigned short* Wp = (k0 < 512) ? WrT : WoT;
        const int kk = k0 & 511;
        #pragma unroll
        for (int i = 0; i < 2; ++i) {
            int chunk = (wave << 1) + i;
            gload16(Ap + (size_t)rowA[i] * HH + kk + sColSwz, Asb + chunk * 512);
            gload16(Wp + (size_t)colB[i] * HH + kk + sColSwz, Bsb + chunk * 512);
        }
    };

    auto COMPUTE = [&](const unsigned short* Asb, const unsigned short* Bsb) {
        short8 af[4], bfv[4];
        #pragma unroll
        for (int m = 0; m < 4; ++m)
            af[m] = *(const short8*)(Asb + (wr * 64 + m * 16 + l16) * 32 + xorslot);
        #pragma unroll
        for (int n = 0; n < 4; ++n)
            bfv[n] = *(const short8*)(Bsb + (wc * 64 + n * 16 + l16) * 32 + xorslot);
        #pragma unroll
        for (int m = 0; m < 4; ++m)
            #pragma unroll
            for (int n = 0; n < 4; ++n)
                acc[m][n] = __builtin_amdgcn_mfma_f32_16x16x32_bf16(af[m], bfv[n], acc[m][n], 0, 0, 0);
    };

    unsigned short *A0 = As, *A1 = As + 4096, *A2 = As + 8192;
    unsigned short *B0 = Bs, *B1 = Bs + 4096, *B2 = Bs + 8192;

    // Prologue: depth-2 prefetch (8 loads/wave in flight)
    STAGE(A0, B0, 0);
    STAGE(A1, B1, 1);

    #pragma unroll 1
    for (int t = 0; t < 31; ++t) {
        // Wait only for tile-t's 4 loads; tile-(t+1)'s stay in flight.
        asm volatile("s_waitcnt vmcnt(4)" ::: "memory");
        __builtin_amdgcn_s_barrier();          // all waves' tile-t loads landed
        __builtin_amdgcn_sched_barrier(0);     // pin ds_reads below the barrier
        if (t + 2 < 32) STAGE(A2, B2, t + 2);  // buf held tile t-1; all its readers done
        COMPUTE(A0, B0);
        unsigned short* tA = A0; A0 = A1; A1 = A2; A2 = tA;
        unsigned short* tB = B0; B0 = B1; B1 = B2; B2 = tB;
    }
    // Final tile: drain everything.
    asm volatile("s_waitcnt vmcnt(0)" ::: "memory");
    __builtin_amdgcn_s_barrier();
    __builtin_amdgcn_sched_barrier(0);
    COMPUTE(A0, B0);

    // Epilogue: + bias (+relu) + resid; optional f32 / bf16 stores
    const float*          residf = (const float*)residv;
    const unsigned short* residb = (const unsigned short*)residv;
    float bias_n[4];
    #pragma unroll
    for (int n = 0; n < 4; ++n) bias_n[n] = bias[col0 + wc * 64 + n * 16 + l16];

    #pragma unroll
    for (int m = 0; m < 4; ++m) {
        #pragma unroll
        for (int j = 0; j < 4; ++j) {
            int row = row0 + wr * 64 + m * 16 + lq * 4 + j;
            if (row >= NN) continue;
            #pragma unroll
            for (int n = 0; n < 4; ++n) {
                int col = col0 + wc * 64 + n * 16 + l16;
                size_t off = (size_t)row * HH + col;
                float v = acc[m][n][j] + bias_n[n];
                if (RELU) v = fmaxf(v, 0.f);
                v += RB16 ? b2f(residb[off]) : residf[off];
                if (WF32) out[off] = v;
                if (WB16) outb[off] = f2b(v);
            }
        }
    }
}

extern "C" void kernel_launch(void* const* d_in, const int* in_sizes, int n_in,
                              void* d_out, int out_size, void* d_ws, size_t ws_size,
                              hipStream_t stream) {
    const float* x   = (const float*)d_in[0];
    const int*   ei  = (const int*)d_in[1];
    const int*   src = ei;
    const int*   dst = ei + EE;
    const float* w_rel1  = (const float*)d_in[2];
    const float* b_rel1  = (const float*)d_in[3];
    const float* w_root1 = (const float*)d_in[4];
    const float* w_rel2  = (const float*)d_in[5];
    const float* b_rel2  = (const float*)d_in[6];
    const float* w_root2 = (const float*)d_in[7];
    const float* w_rel3  = (const float*)d_in[8];
    const float* b_rel3  = (const float*)d_in[9];
    const float* w_root3 = (const float*)d_in[10];
    const float* w_rel4  = (const float*)d_in[11];
    const float* b_rel4  = (const float*)d_in[12];
    const float* w_root4 = (const float*)d_in[13];

    const size_t NH = (size_t)NN * HH;
    float*          W0   = (float*)d_ws;                 // x1 (f32), then x3 (f32)
    unsigned short* XB   = (unsigned short*)(W0 + NH);   // bf16 ping (x1, then x3)
    unsigned short* XB2  = XB + NH;                      // bf16 pong (x2)
    unsigned short* AGB  = XB2 + NH;                     // agg bf16
    unsigned short* WT   = AGB + NH;                     // 6 transposed bf16 weights
    float*          agg0 = (float*)(WT + 6 * 262144);
    int*            csr  = (int*)(agg0 + NN);
    int* deg       = csr;
    int* start     = csr + NN;
    int* cursor    = start + NN + 1;
    int* eidx      = cursor + NN;
    int* blockSums = eidx + EE;
    float* out = (float*)d_out;

    unsigned short* WrT2 = WT;
    unsigned short* WoT2 = WT + 1 * 262144;
    unsigned short* WrT3 = WT + 2 * 262144;
    unsigned short* WoT3 = WT + 3 * 262144;
    unsigned short* WrT4 = WT + 4 * 262144;
    unsigned short* WoT4 = WT + 5 * 262144;

    const int gGemm = 3128;  // 782 m-tiles x 4 n-tiles, XCD-chunked in-kernel

    // ---- CSR build ----
    hipMemsetAsync(deg, 0, NN * sizeof(int), stream);
    histo_deg<<<(EE + 255) / 256, 256, 0, stream>>>(dst, deg);
    scan_reduce<<<NB_SCAN, 256, 0, stream>>>(deg, blockSums);
    scan_top<<<1, 128, 0, stream>>>(blockSums, start);
    scan_down<<<NB_SCAN, 256, 0, stream>>>(deg, blockSums, start, cursor);
    csr_fill<<<(EE + 255) / 256, 256, 0, stream>>>(src, dst, cursor, eidx);

    // ---- Weights -> transposed bf16 ----
    w_transpose<<<1024, 256, 0, stream>>>(w_rel2,  WrT2);
    w_transpose<<<1024, 256, 0, stream>>>(w_root2, WoT2);
    w_transpose<<<1024, 256, 0, stream>>>(w_rel3,  WrT3);
    w_transpose<<<1024, 256, 0, stream>>>(w_root3, WoT3);
    w_transpose<<<1024, 256, 0, stream>>>(w_rel4,  WrT4);
    w_transpose<<<1024, 256, 0, stream>>>(w_root4, WoT4);

    // ---- Layer 1: x1 -> W0 (f32) + XB (bf16) ----
    gather_scalar<<<(NN + 255) / 256, 256, 0, stream>>>(x, start, eidx, agg0);
    layer1_expand<<<50000, 256, 0, stream>>>(x, agg0, w_rel1, b_rel1, w_root1, W0, XB);

    // ---- Layer 2: x2 = relu(conv(x1)) + x1 -> XB2 (bf16 only) ----
    gather_rows_b<<<25000, 256, 0, stream>>>(XB, start, eidx, AGB);
    gemm_mfma<true, false, false, true><<<gGemm, 256, 0, stream>>>(
        AGB, XB, WrT2, WoT2, b_rel2, W0, nullptr, XB2);

    // ---- Layer 3: x3 = conv(x2) + x2 -> W0 (f32) + XB (bf16); resid = bf16 x2 ----
    gather_rows_b<<<25000, 256, 0, stream>>>(XB2, start, eidx, AGB);
    gemm_mfma<false, true, true, true><<<gGemm, 256, 0, stream>>>(
        AGB, XB2, WrT3, WoT3, b_rel3, XB2, W0, XB);

    // ---- Layer 4: x4 = conv(x3) + x3 -> d_out (f32); resid = f32 x3 ----
    gather_rows_b<<<25000, 256, 0, stream>>>(XB, start, eidx, AGB);
    gemm_mfma<false, false, true, false><<<gGemm, 256, 0, stream>>>(
        AGB, XB, WrT4, WoT4, b_rel4, W0, out, nullptr);
}